// Round 10
// baseline (226.660 us; speedup 1.0000x reference)
//
#include <hip/hip_runtime.h>
#include <hip/hip_bf16.h>

typedef __hip_bfloat16 bf16;
typedef __attribute__((ext_vector_type(8))) short bf16x8;   // 8 bf16 = 4 VGPRs
typedef __attribute__((ext_vector_type(4))) float f32x4;

constexpr int Bc  = 2;
constexpr int Sc  = 2048;
constexpr int Dc  = 1024;
constexpr int Hc  = 16;
constexpr int DHc = 64;
constexpr int BS  = Bc * Sc;   // 4096 rows
constexpr int NT  = Sc / 64;   // 32 key tiles

__device__ __forceinline__ float bs2f(unsigned short u) {
    union { unsigned int i; float f; } v; v.i = ((unsigned int)u) << 16; return v.f;
}
__device__ __forceinline__ short f2bs(float x) {
    bf16 h = __float2bfloat16(x);
    return *reinterpret_cast<short*>(&h);
}

// async global->LDS, 16B per lane. LDS dest is wave-uniform base + lane*16.
typedef const __attribute__((address_space(1))) unsigned int* as1_u32p;
typedef __attribute__((address_space(3))) unsigned int* as3_u32p;
__device__ __forceinline__ void gl_lds16(const void* g, void* l) {
    __builtin_amdgcn_global_load_lds((as1_u32p)g, (as3_u32p)l, 16, 0, 0);
}

// ---------------------------------------------------------------------------
// prep: fused {cast x f32->bf16} + {transpose+cast 4 weight matrices}.
// Blocks [0,4096): cast chunk; blocks [4096,5120): transpose tile.
// ---------------------------------------------------------------------------
__global__ __launch_bounds__(256) void prep(
    const float* __restrict__ x, short* __restrict__ xb,
    const float* __restrict__ w0, const float* __restrict__ w1,
    const float* __restrict__ w2, const float* __restrict__ w3,
    short* __restrict__ WT)
{
    __shared__ float T[64][65];
    const int i = blockIdx.x;
    const int t = threadIdx.x;

    if (i < 4096) {   // cast path
        const int off = i * 1024 + t * 4;
        const float4 v = *(const float4*)(x + off);
        ushort4 o;
        o.x = (unsigned short)f2bs(v.x);
        o.y = (unsigned short)f2bs(v.y);
        o.z = (unsigned short)f2bs(v.z);
        o.w = (unsigned short)f2bs(v.w);
        *(ushort4*)(xb + off) = o;
        return;
    }

    // transpose path
    const int idx = i - 4096;            // 0..1023
    const int z  = idx >> 8;             // weight select
    const int k0 = (idx & 15) * 64;
    const int n0 = ((idx >> 4) & 15) * 64;
    const float* in = (z == 0) ? w0 : (z == 1) ? w1 : (z == 2) ? w2 : w3;
    short* out = WT + (size_t)z * 1024 * 1024;
    #pragma unroll
    for (int it = 0; it < 4; ++it) {
        const int s = it * 256 + t;
        const int r = s >> 4, c = (s & 15) * 4;
        *(float4*)&T[r][c] = *(const float4*)(in + (size_t)(k0 + r) * 1024 + n0 + c);
    }
    __syncthreads();
    #pragma unroll
    for (int it = 0; it < 4; ++it) {
        const int s = it * 256 + t;
        const int rr = s >> 4, cc = (s & 15) * 4;   // rr: n-local, cc: k-local
        ushort4 o;
        o.x = (unsigned short)f2bs(T[cc + 0][rr]);
        o.y = (unsigned short)f2bs(T[cc + 1][rr]);
        o.z = (unsigned short)f2bs(T[cc + 2][rr]);
        o.w = (unsigned short)f2bs(T[cc + 3][rr]);
        *(ushort4*)(out + (size_t)(n0 + rr) * 1024 + k0 + cc) = o;
    }
}

// ---------------------------------------------------------------------------
// MFMA GEMM (m97 structure): C[z] = (A @ BT[z]^T + bias[z]) * (z==0 ? sc0 : 1)
// 128x128 tile, BK=64, 256 thr = 4 waves of 64x64. Used for QKV (3 blocks/CU).
// ---------------------------------------------------------------------------
__global__ __launch_bounds__(256, 3) void gemm_bt(
    const short* __restrict__ A, const short* __restrict__ BTbase,
    const float* __restrict__ b0, const float* __restrict__ b1,
    const float* __restrict__ b2, short* __restrict__ Cbase,
    const float sc0)
{
    __shared__ __align__(16) short As[128 * 64];
    __shared__ __align__(16) short Bs[128 * 64];

    const int z = blockIdx.z;
    const short* BT = BTbase + (size_t)z * 1024 * 1024;
    const float* bias = (z == 0) ? b0 : (z == 1) ? b1 : b2;
    const float sc = (z == 0) ? sc0 : 1.0f;
    short* C = Cbase + (size_t)z * BS * Dc;

    const int t = threadIdx.x;
    const int lane = t & 63, w = t >> 6;
    const int quad = lane >> 4, l16 = lane & 15;
    const int wm = (w & 1) * 64, wn = (w >> 1) * 64;
    const int row0 = blockIdx.y * 128;
    const int col0 = blockIdx.x * 128;
    const int sw = l16 & 7;   // fragment-read swizzle key (row & 7)

    f32x4 acc[4][4] = {};

    for (int kt = 0; kt < 1024; kt += 64) {
        __syncthreads();
        #pragma unroll
        for (int i = 0; i < 4; ++i) {
            const int f = i * 256 + t;            // 16B slot index 0..1023
            const int r = f >> 3;                 // tile row 0..127
            const int g = (f & 7) ^ (r & 7);      // swizzled global seg
            short* lb = &As[(i * 256 + w * 64) * 8];   // wave-uniform base
            gl_lds16(A + (size_t)(row0 + r) * 1024 + kt + g * 8, lb);
            short* lb2 = &Bs[(i * 256 + w * 64) * 8];
            gl_lds16(BT + (size_t)(col0 + r) * 1024 + kt + g * 8, lb2);
        }
        __syncthreads();   // drains vmcnt before use
        #pragma unroll
        for (int ks = 0; ks < 2; ++ks) {
            bf16x8 av[4], bv[4];
            #pragma unroll
            for (int mt = 0; mt < 4; ++mt) {
                const int r = wm + mt * 16 + l16;
                av[mt] = *(const bf16x8*)&As[r * 64 + ((ks * 4 + quad) ^ sw) * 8];
            }
            #pragma unroll
            for (int nt = 0; nt < 4; ++nt) {
                const int r = wn + nt * 16 + l16;
                bv[nt] = *(const bf16x8*)&Bs[r * 64 + ((ks * 4 + quad) ^ sw) * 8];
            }
            #pragma unroll
            for (int mt = 0; mt < 4; ++mt)
                #pragma unroll
                for (int nt = 0; nt < 4; ++nt)
                    acc[mt][nt] = __builtin_amdgcn_mfma_f32_16x16x32_bf16(
                        av[mt], bv[nt], acc[mt][nt], 0, 0, 0);
        }
    }

    float bvv[4];
    #pragma unroll
    for (int nt = 0; nt < 4; ++nt) bvv[nt] = bias[col0 + wn + nt * 16 + l16];
    #pragma unroll
    for (int mt = 0; mt < 4; ++mt)
        #pragma unroll
        for (int reg = 0; reg < 4; ++reg) {
            const size_t row = row0 + wm + mt * 16 + quad * 4 + reg;
            #pragma unroll
            for (int nt = 0; nt < 4; ++nt) {
                const int col = col0 + wn + nt * 16 + l16;
                C[row * 1024 + col] = f2bs((acc[mt][nt][reg] + bvv[nt]) * sc);
            }
        }
}

// ---------------------------------------------------------------------------
// BN=64 GEMM variant for the AO projection: C = A @ BT^T + bias.
// 128x64 tile -> grid (16,32) = 512 blocks = 2 blocks/CU (the 128x128 AO
// grid was 256 blocks = 1/CU: m97's structure needs cross-block overlap to
// hide its barrier drains; at 1/CU they are fully exposed).
// 4 waves of 64 rows x 32 cols (mt 4, nt 2).
// ---------------------------------------------------------------------------
__global__ __launch_bounds__(256, 3) void gemm_bt_n64(
    const short* __restrict__ A, const short* __restrict__ BT,
    const float* __restrict__ bias, short* __restrict__ C)
{
    __shared__ __align__(16) short As[128 * 64];
    __shared__ __align__(16) short Bs[64 * 64];

    const int t = threadIdx.x;
    const int lane = t & 63, w = t >> 6;
    const int quad = lane >> 4, l16 = lane & 15;
    const int wm = (w & 1) * 64, wn = (w >> 1) * 32;
    const int row0 = blockIdx.y * 128;
    const int col0 = blockIdx.x * 64;
    const int sw = l16 & 7;

    f32x4 acc[4][2] = {};

    for (int kt = 0; kt < 1024; kt += 64) {
        __syncthreads();
        #pragma unroll
        for (int i = 0; i < 4; ++i) {
            const int f = i * 256 + t;
            const int r = f >> 3;
            const int g = (f & 7) ^ (r & 7);
            gl_lds16(A + (size_t)(row0 + r) * 1024 + kt + g * 8,
                     &As[(i * 256 + w * 64) * 8]);
        }
        #pragma unroll
        for (int i = 0; i < 2; ++i) {
            const int f = i * 256 + t;
            const int r = f >> 3;
            const int g = (f & 7) ^ (r & 7);
            gl_lds16(BT + (size_t)(col0 + r) * 1024 + kt + g * 8,
                     &Bs[(i * 256 + w * 64) * 8]);
        }
        __syncthreads();
        #pragma unroll
        for (int ks = 0; ks < 2; ++ks) {
            bf16x8 av[4], bv[2];
            #pragma unroll
            for (int mt = 0; mt < 4; ++mt) {
                const int r = wm + mt * 16 + l16;
                av[mt] = *(const bf16x8*)&As[r * 64 + ((ks * 4 + quad) ^ sw) * 8];
            }
            #pragma unroll
            for (int nt = 0; nt < 2; ++nt) {
                const int r = wn + nt * 16 + l16;
                bv[nt] = *(const bf16x8*)&Bs[r * 64 + ((ks * 4 + quad) ^ sw) * 8];
            }
            #pragma unroll
            for (int mt = 0; mt < 4; ++mt)
                #pragma unroll
                for (int nt = 0; nt < 2; ++nt)
                    acc[mt][nt] = __builtin_amdgcn_mfma_f32_16x16x32_bf16(
                        av[mt], bv[nt], acc[mt][nt], 0, 0, 0);
        }
    }

    float bvv[2];
    #pragma unroll
    for (int nt = 0; nt < 2; ++nt) bvv[nt] = bias[col0 + wn + nt * 16 + l16];
    #pragma unroll
    for (int mt = 0; mt < 4; ++mt)
        #pragma unroll
        for (int reg = 0; reg < 4; ++reg) {
            const size_t row = row0 + wm + mt * 16 + quad * 4 + reg;
            #pragma unroll
            for (int nt = 0; nt < 2; ++nt) {
                const int col = col0 + wn + nt * 16 + l16;
                C[row * 1024 + col] = f2bs(acc[mt][reg == reg ? nt : nt][reg] + bvv[nt]);
            }
        }
}

// ---------------------------------------------------------------------------
// Pair-SEQUENTIAL MFMA flash attention (R8/R9 structure), strict-upper mask,
// vmean fused as concurrent blocks (grid (16,17,2)).
// R10 change: K is NOT staged in LDS. kf fragments load directly from global;
// with the XCD remap each (b,h)'s K (256KB) is resident in the local 4MB L2
// (R9 FETCH 15.9MB proves residency; R3's failure predated the remap and was
// HBM-miss K). kf(t+1) loads issue right after QK(t)'s MFMAs (WAR-safe) and
// complete during softmax+PV+staging+barrier -- same lead-time pattern as the
// existing pv prefetch. Removes 8 b128 reads + 2 b128 writes per wave-step
// from the ~70%-busy LDS pipe (the measured attn limiter: R2@8 and R6@16
// waves/CU both 57us) and ~2.2M of the bank conflicts (R3 measurement).
// Per-row coalescing: 4 contiguous 16B lanes per K-row = one 64B transaction.
// ---------------------------------------------------------------------------
__global__ __launch_bounds__(256, 3) void attn_mfma(
    const short* __restrict__ Qg, const short* __restrict__ Kg,
    const short* __restrict__ Vg, short* __restrict__ CTX)
{
    __shared__ __align__(16) short VsT[2][64][72];   // [buf][d][pi(key)]
    __shared__ __align__(16) short Ps[4][16][72];    // per-wave P scratch
    __shared__ float red[4][64];                     // vmean reduction

    const int tid  = threadIdx.x;

    if (blockIdx.y == 16) {   // ---- vmean path (concurrent) ----
        const int h = blockIdx.x, b = blockIdx.z;
        const int dh = tid & 63, ck = tid >> 6;      // 4 chunks of 512 keys
        float s = 0.f;
        const short* vp = Vg + ((size_t)b * Sc + ck * 512) * Dc + h * DHc + dh;
        for (int j = 0; j < 512; ++j) s += bs2f(vp[(size_t)j * Dc]);
        red[ck][dh] = s;
        __syncthreads();
        if (ck == 0) {
            const float tot = (red[0][dh] + red[1][dh] + red[2][dh] + red[3][dh]) * (1.f / Sc);
            CTX[((size_t)b * Sc + Sc - 1) * Dc + h * DHc + dh] = f2bs(tot);
        }
        return;
    }

    // ---- attn path ----
    const int lane = tid & 63, w = tid >> 6;         // w 0..3
    const int quad = lane >> 4, l16 = lane & 15;

    // XCD-locality decode (R9: flat = x+16y+272z -> xcd = x&7; each XCD owns
    // 4 complete (b,h) groups, all 16 pairs)
    const int xcd   = blockIdx.x & 7;
    const int local = (blockIdx.x >> 3) + 2 * blockIdx.y + 32 * blockIdx.z;  // 0..63
    const int bh    = xcd * 4 + (local >> 4);
    const int p     = local & 15;
    const int h     = bh & 15;
    const int b     = bh >> 4;
    const size_t rb = (size_t)b * Sc;
    const int cb = h * DHc;

    // V staging: thread stages key row skey, d-segs sseg & sseg+32
    const int skey = tid & 63, sseg = (tid >> 6) * 8;
    const int pkey = ((skey & 15) << 2) | (skey >> 4);   // pi(skey)

    bf16x8 ones;
    #pragma unroll
    for (int e = 0; e < 8; ++e) ones[e] = (short)0x3F80;   // bf16 1.0

    const size_t tstride = (size_t)64 * Dc;

    #pragma unroll 1
    for (int ph = 0; ph < 2; ++ph) {
        const int myq = ph ? (NT - 1 - p) : p;   // q-tile index 0..31
        const int t0  = myq;
        const int q0  = myq * 64;

        bf16x8 qf[2];
        {
            const short* qp = Qg + (rb + q0 + w * 16 + l16) * (size_t)Dc + cb + quad * 8;
            qf[0] = *(const bf16x8*)(qp);
            qf[1] = *(const bf16x8*)(qp + 32);
        }
        f32x4 lacc = {};
        f32x4 O[4] = {};

        // per-lane K fragment pointer for tile t: row l16 (+nt*16), seg quad*8 (+ks*32)
        const short* kfp = Kg + (rb + (size_t)t0 * 64 + l16) * Dc + cb + quad * 8;
        // V staging pointer
        const short* vp = Vg + (rb + (size_t)t0 * 64 + skey) * Dc + cb + sseg;

        // K fragments for tile t0 (global/L2 direct)
        bf16x8 kf[2][4];
        #pragma unroll
        for (int ks = 0; ks < 2; ++ks)
            #pragma unroll
            for (int nt = 0; nt < 4; ++nt)
                kf[ks][nt] = *(const bf16x8*)(kfp + (size_t)nt * 16 * Dc + ks * 32);

        if (ph) __syncthreads();   // phase A waves may still be reading VsT

        {   // stage first V tile t0 into buf t0&1
            const int buf = t0 & 1;
            const bf16x8 v0v = *(const bf16x8*)(vp);
            const bf16x8 v1v = *(const bf16x8*)(vp + 32);
            #pragma unroll
            for (int e = 0; e < 8; ++e) {
                VsT[buf][sseg + e][pkey]      = v0v[e];
                VsT[buf][sseg + 32 + e][pkey] = v1v[e];
            }
        }
        __syncthreads();

        for (int t = t0; t < NT; ++t) {
            const int cur = t & 1;
            const bool havenext = (t + 1 < NT);
            bf16x8 pv0, pv1;
            if (havenext) {   // V register prefetch of tile t+1
                pv0 = *(const bf16x8*)(vp + tstride);
                pv1 = *(const bf16x8*)(vp + tstride + 32);
            }

            // ---- QK^T ----
            f32x4 S[4] = {};
            __builtin_amdgcn_s_setprio(1);
            #pragma unroll
            for (int ks = 0; ks < 2; ++ks)
                #pragma unroll
                for (int nt = 0; nt < 4; ++nt)
                    S[nt] = __builtin_amdgcn_mfma_f32_16x16x32_bf16(
                        qf[ks], kf[ks][nt], S[nt], 0, 0, 0);
            __builtin_amdgcn_s_setprio(0);

            // reload kf with tile t+1 (regs free after MFMA issue; loads
            // complete during softmax+PV+staging+barrier, all L2-local)
            if (havenext) {
                const short* kp_ = kfp + tstride;
                #pragma unroll
                for (int ks = 0; ks < 2; ++ks)
                    #pragma unroll
                    for (int nt = 0; nt < 4; ++nt)
                        kf[ks][nt] = *(const bf16x8*)(kp_ + (size_t)nt * 16 * Dc + ks * 32);
            }

            // ---- softmax (Q pre-scaled by 0.125*log2e; clamp 115.4; mask -126) ----
            #pragma unroll
            for (int nt = 0; nt < 4; ++nt) {
                #pragma unroll
                for (int reg = 0; reg < 4; ++reg) {
                    float s = fminf(S[nt][reg], 115.4f);
                    if (t == t0) {
                        const int col = t * 64 + nt * 16 + l16;
                        const int row = q0 + w * 16 + quad * 4 + reg;
                        s = (col > row) ? s : -126.0f;
                    }
                    S[nt][reg] = exp2f(s);
                }
            }

            // publish P: per output row, pack 4 values (phys cols 4*l16+0..3) -> b64
            #pragma unroll
            for (int reg = 0; reg < 4; ++reg) {
                const __hip_bfloat162 lo = __float22bfloat162_rn(make_float2(S[0][reg], S[1][reg]));
                const __hip_bfloat162 hi = __float22bfloat162_rn(make_float2(S[2][reg], S[3][reg]));
                uint2 u;
                u.x = *reinterpret_cast<const unsigned int*>(&lo);
                u.y = *reinterpret_cast<const unsigned int*>(&hi);
                *(uint2*)&Ps[w][quad * 4 + reg][l16 * 4] = u;
            }

            // ---- PV + l on the matrix pipe ----
            __builtin_amdgcn_s_setprio(1);
            #pragma unroll
            for (int ks = 0; ks < 2; ++ks) {
                const bf16x8 pf = *(const bf16x8*)&Ps[w][l16][ks * 32 + quad * 8];
                lacc = __builtin_amdgcn_mfma_f32_16x16x32_bf16(pf, ones, lacc, 0, 0, 0);
                #pragma unroll
                for (int nt = 0; nt < 4; ++nt) {
                    const bf16x8 vf = *(const bf16x8*)&VsT[cur][nt * 16 + l16][ks * 32 + quad * 8];
                    O[nt] = __builtin_amdgcn_mfma_f32_16x16x32_bf16(pf, vf, O[nt], 0, 0, 0);
                }
            }
            __builtin_amdgcn_s_setprio(0);

            if (havenext) {   // stage V tile t+1 into the other buffer, ONE barrier
                const int nb = cur ^ 1;
                #pragma unroll
                for (int e = 0; e < 8; ++e) {
                    VsT[nb][sseg + e][pkey]      = pv0[e];
                    VsT[nb][sseg + 32 + e][pkey] = pv1[e];
                }
                __syncthreads();
            }
            kfp += tstride;
            vp  += tstride;
        }

        // normalize + store; skip row S-1 (owned by the fused vmean blocks)
        float inv[4];
        #pragma unroll
        for (int reg = 0; reg < 4; ++reg) inv[reg] = 1.0f / lacc[reg];
        #pragma unroll
        for (int nt = 0; nt < 4; ++nt)
            #pragma unroll
            for (int reg = 0; reg < 4; ++reg) {
                const int lr = q0 + w * 16 + quad * 4 + reg;
                if (lr != Sc - 1)
                    CTX[(rb + lr) * Dc + cb + nt * 16 + l16] = f2bs(O[nt][reg] * inv[reg]);
            }
    }
}

// ---------------------------------------------------------------------------
// out = LayerNorm(x + attn_out) * gamma + beta; x f32, AO bf16, out f32
// ---------------------------------------------------------------------------
__global__ __launch_bounds__(256, 4) void resid_ln(
    const float* __restrict__ X, const short* __restrict__ AO,
    const float* __restrict__ gamma, const float* __restrict__ beta,
    float* __restrict__ out)
{
    const int r = blockIdx.x;
    const int t = threadIdx.x;
    const size_t base = (size_t)r * Dc + t * 4;

    const float4 x4 = *(const float4*)(X + base);
    const ushort4 a4 = *(const ushort4*)(AO + base);
    float y[4];
    y[0] = x4.x + bs2f(a4.x);
    y[1] = x4.y + bs2f(a4.y);
    y[2] = x4.z + bs2f(a4.z);
    y[3] = x4.w + bs2f(a4.w);

    float s  = y[0] + y[1] + y[2] + y[3];
    float s2 = y[0]*y[0] + y[1]*y[1] + y[2]*y[2] + y[3]*y[3];
    #pragma unroll
    for (int off = 1; off < 64; off <<= 1) {
        s  += __shfl_xor(s,  off, 64);
        s2 += __shfl_xor(s2, off, 64);
    }
    __shared__ float red[8];
    const int w = t >> 6;
    if ((t & 63) == 0) { red[w] = s; red[4 + w] = s2; }
    __syncthreads();
    s  = red[0] + red[1] + red[2] + red[3];
    s2 = red[4] + red[5] + red[6] + red[7];

    const float mu   = s * (1.0f / Dc);
    const float rstd = rsqrtf(s2 * (1.0f / Dc) - mu * mu + 1e-6f);

    const float4 g4 = *(const float4*)(gamma + t * 4);
    const float4 b4 = *(const float4*)(beta  + t * 4);
    float4 o;
    o.x = (y[0] - mu) * rstd * g4.x + b4.x;
    o.y = (y[1] - mu) * rstd * g4.y + b4.y;
    o.z = (y[2] - mu) * rstd * g4.z + b4.z;
    o.w = (y[3] - mu) * rstd * g4.w + b4.w;
    *(float4*)(out + base) = o;
}

// ---------------------------------------------------------------------------
extern "C" void kernel_launch(void* const* d_in, const int* in_sizes, int n_in,
                              void* d_out, int out_size, void* d_ws, size_t ws_size,
                              hipStream_t stream)
{
    (void)in_sizes; (void)n_in; (void)out_size; (void)ws_size;
    const float* x     = (const float*)d_in[0];
    const float* Wq    = (const float*)d_in[1];
    const float* bq    = (const float*)d_in[2];
    const float* Wk    = (const float*)d_in[3];
    const float* bk    = (const float*)d_in[4];
    const float* Wv    = (const float*)d_in[5];
    const float* bv    = (const float*)d_in[6];
    const float* Wo    = (const float*)d_in[7];
    const float* bo    = (const float*)d_in[8];
    const float* gamma = (const float*)d_in[9];
    const float* beta  = (const float*)d_in[10];
    float* out = (float*)d_out;

    const size_t matN = (size_t)BS * Dc;       // 4,194,304
    const size_t wN   = (size_t)Dc * Dc;       // 1,048,576
    short* xb = (short*)d_ws;                  // 8 MB
    short* WT = xb + matN;                     // 8 MB (4 transposed weights)
    short* Qb = WT + 4 * wN;                   // 8 MB
    short* Kb = Qb + matN;                     // 8 MB
    short* Vb = Kb + matN;                     // 8 MB
    short* Cx = Vb + matN;                     // 8 MB
    short* AO = Qb;                            // Q dead after attention

    prep<<<5120, 256, 0, stream>>>(x, xb, Wq, Wk, Wv, Wo, WT);

    dim3 gq(Dc / 128, BS / 128, 3);            // (8, 32, 3) = 768 blocks, 3/CU
    gemm_bt<<<gq, 256, 0, stream>>>(xb, WT, bq, bk, bv, Qb, 0.18033688f);

    dim3 ga(16, 17, 2);                        // 512 attn blocks + 32 fused vmean
    attn_mfma<<<ga, 256, 0, stream>>>(Qb, Kb, Vb, Cx);

    dim3 go(Dc / 64, BS / 128, 1);             // (16, 32) = 512 blocks, 2/CU
    gemm_bt_n64<<<go, 256, 0, stream>>>(Cx, WT + 3 * wN, bo, AO);

    resid_ln<<<BS, 256, 0, stream>>>(x, AO, gamma, beta, out);
}

// Round 11
// 195.119 us; speedup vs baseline: 1.1617x; 1.1617x over previous
//
#include <hip/hip_runtime.h>
#include <hip/hip_bf16.h>

typedef __hip_bfloat16 bf16;
typedef __attribute__((ext_vector_type(8))) short bf16x8;   // 8 bf16 = 4 VGPRs
typedef __attribute__((ext_vector_type(4))) float f32x4;

constexpr int Bc  = 2;
constexpr int Sc  = 2048;
constexpr int Dc  = 1024;
constexpr int Hc  = 16;
constexpr int DHc = 64;
constexpr int BS  = Bc * Sc;   // 4096 rows
constexpr int NT  = Sc / 64;   // 32 key tiles

__device__ __forceinline__ float bs2f(unsigned short u) {
    union { unsigned int i; float f; } v; v.i = ((unsigned int)u) << 16; return v.f;
}
__device__ __forceinline__ short f2bs(float x) {
    bf16 h = __float2bfloat16(x);
    return *reinterpret_cast<short*>(&h);
}

// async global->LDS, 16B per lane. LDS dest is wave-uniform base + lane*16.
typedef const __attribute__((address_space(1))) unsigned int* as1_u32p;
typedef __attribute__((address_space(3))) unsigned int* as3_u32p;
__device__ __forceinline__ void gl_lds16(const void* g, void* l) {
    __builtin_amdgcn_global_load_lds((as1_u32p)g, (as3_u32p)l, 16, 0, 0);
}

// ---------------------------------------------------------------------------
// prep: fused {cast x f32->bf16} + {transpose+cast 4 weight matrices}.
// Blocks [0,4096): cast chunk; blocks [4096,5120): transpose tile.
// ---------------------------------------------------------------------------
__global__ __launch_bounds__(256) void prep(
    const float* __restrict__ x, short* __restrict__ xb,
    const float* __restrict__ w0, const float* __restrict__ w1,
    const float* __restrict__ w2, const float* __restrict__ w3,
    short* __restrict__ WT)
{
    __shared__ float T[64][65];
    const int i = blockIdx.x;
    const int t = threadIdx.x;

    if (i < 4096) {   // cast path
        const int off = i * 1024 + t * 4;
        const float4 v = *(const float4*)(x + off);
        ushort4 o;
        o.x = (unsigned short)f2bs(v.x);
        o.y = (unsigned short)f2bs(v.y);
        o.z = (unsigned short)f2bs(v.z);
        o.w = (unsigned short)f2bs(v.w);
        *(ushort4*)(xb + off) = o;
        return;
    }

    // transpose path
    const int idx = i - 4096;            // 0..1023
    const int z  = idx >> 8;             // weight select
    const int k0 = (idx & 15) * 64;
    const int n0 = ((idx >> 4) & 15) * 64;
    const float* in = (z == 0) ? w0 : (z == 1) ? w1 : (z == 2) ? w2 : w3;
    short* out = WT + (size_t)z * 1024 * 1024;
    #pragma unroll
    for (int it = 0; it < 4; ++it) {
        const int s = it * 256 + t;
        const int r = s >> 4, c = (s & 15) * 4;
        *(float4*)&T[r][c] = *(const float4*)(in + (size_t)(k0 + r) * 1024 + n0 + c);
    }
    __syncthreads();
    #pragma unroll
    for (int it = 0; it < 4; ++it) {
        const int s = it * 256 + t;
        const int rr = s >> 4, cc = (s & 15) * 4;   // rr: n-local, cc: k-local
        ushort4 o;
        o.x = (unsigned short)f2bs(T[cc + 0][rr]);
        o.y = (unsigned short)f2bs(T[cc + 1][rr]);
        o.z = (unsigned short)f2bs(T[cc + 2][rr]);
        o.w = (unsigned short)f2bs(T[cc + 3][rr]);
        *(ushort4*)(out + (size_t)(n0 + rr) * 1024 + k0 + cc) = o;
    }
}

// ---------------------------------------------------------------------------
// MFMA GEMM (m97 structure): C[z] = (A @ BT[z]^T + bias[z]) * (z==0 ? sc0 : 1)
// 128x128 tile, BK=64, 256 thr = 4 waves of 64x64. Used for QKV (3 blocks/CU).
// ---------------------------------------------------------------------------
__global__ __launch_bounds__(256, 3) void gemm_bt(
    const short* __restrict__ A, const short* __restrict__ BTbase,
    const float* __restrict__ b0, const float* __restrict__ b1,
    const float* __restrict__ b2, short* __restrict__ Cbase,
    const float sc0)
{
    __shared__ __align__(16) short As[128 * 64];
    __shared__ __align__(16) short Bs[128 * 64];

    const int z = blockIdx.z;
    const short* BT = BTbase + (size_t)z * 1024 * 1024;
    const float* bias = (z == 0) ? b0 : (z == 1) ? b1 : b2;
    const float sc = (z == 0) ? sc0 : 1.0f;
    short* C = Cbase + (size_t)z * BS * Dc;

    const int t = threadIdx.x;
    const int lane = t & 63, w = t >> 6;
    const int quad = lane >> 4, l16 = lane & 15;
    const int wm = (w & 1) * 64, wn = (w >> 1) * 64;
    const int row0 = blockIdx.y * 128;
    const int col0 = blockIdx.x * 128;
    const int sw = l16 & 7;   // fragment-read swizzle key (row & 7)

    f32x4 acc[4][4] = {};

    for (int kt = 0; kt < 1024; kt += 64) {
        __syncthreads();
        #pragma unroll
        for (int i = 0; i < 4; ++i) {
            const int f = i * 256 + t;            // 16B slot index 0..1023
            const int r = f >> 3;                 // tile row 0..127
            const int g = (f & 7) ^ (r & 7);      // swizzled global seg
            short* lb = &As[(i * 256 + w * 64) * 8];   // wave-uniform base
            gl_lds16(A + (size_t)(row0 + r) * 1024 + kt + g * 8, lb);
            short* lb2 = &Bs[(i * 256 + w * 64) * 8];
            gl_lds16(BT + (size_t)(col0 + r) * 1024 + kt + g * 8, lb2);
        }
        __syncthreads();   // drains vmcnt before use
        #pragma unroll
        for (int ks = 0; ks < 2; ++ks) {
            bf16x8 av[4], bv[4];
            #pragma unroll
            for (int mt = 0; mt < 4; ++mt) {
                const int r = wm + mt * 16 + l16;
                av[mt] = *(const bf16x8*)&As[r * 64 + ((ks * 4 + quad) ^ sw) * 8];
            }
            #pragma unroll
            for (int nt = 0; nt < 4; ++nt) {
                const int r = wn + nt * 16 + l16;
                bv[nt] = *(const bf16x8*)&Bs[r * 64 + ((ks * 4 + quad) ^ sw) * 8];
            }
            #pragma unroll
            for (int mt = 0; mt < 4; ++mt)
                #pragma unroll
                for (int nt = 0; nt < 4; ++nt)
                    acc[mt][nt] = __builtin_amdgcn_mfma_f32_16x16x32_bf16(
                        av[mt], bv[nt], acc[mt][nt], 0, 0, 0);
        }
    }

    float bvv[4];
    #pragma unroll
    for (int nt = 0; nt < 4; ++nt) bvv[nt] = bias[col0 + wn + nt * 16 + l16];
    #pragma unroll
    for (int mt = 0; mt < 4; ++mt)
        #pragma unroll
        for (int reg = 0; reg < 4; ++reg) {
            const size_t row = row0 + wm + mt * 16 + quad * 4 + reg;
            #pragma unroll
            for (int nt = 0; nt < 4; ++nt) {
                const int col = col0 + wn + nt * 16 + l16;
                C[row * 1024 + col] = f2bs((acc[mt][nt][reg] + bvv[nt]) * sc);
            }
        }
}

// ---------------------------------------------------------------------------
// BN=64 GEMM for the AO projection: C = A @ BT^T + bias.
// 128x64 tile -> grid (16,32) = 512 blocks = 2 blocks/CU.
// R10 measured: non-attn time 146.3 -> 135.0us with this (the 128x128 AO
// grid was 256 blocks = 1/CU; m97's barrier drains need cross-block overlap).
// ---------------------------------------------------------------------------
__global__ __launch_bounds__(256, 3) void gemm_bt_n64(
    const short* __restrict__ A, const short* __restrict__ BT,
    const float* __restrict__ bias, short* __restrict__ C)
{
    __shared__ __align__(16) short As[128 * 64];
    __shared__ __align__(16) short Bs[64 * 64];

    const int t = threadIdx.x;
    const int lane = t & 63, w = t >> 6;
    const int quad = lane >> 4, l16 = lane & 15;
    const int wm = (w & 1) * 64, wn = (w >> 1) * 32;
    const int row0 = blockIdx.y * 128;
    const int col0 = blockIdx.x * 64;
    const int sw = l16 & 7;

    f32x4 acc[4][2] = {};

    for (int kt = 0; kt < 1024; kt += 64) {
        __syncthreads();
        #pragma unroll
        for (int i = 0; i < 4; ++i) {
            const int f = i * 256 + t;
            const int r = f >> 3;
            const int g = (f & 7) ^ (r & 7);
            gl_lds16(A + (size_t)(row0 + r) * 1024 + kt + g * 8,
                     &As[(i * 256 + w * 64) * 8]);
        }
        #pragma unroll
        for (int i = 0; i < 2; ++i) {
            const int f = i * 256 + t;
            const int r = f >> 3;
            const int g = (f & 7) ^ (r & 7);
            gl_lds16(BT + (size_t)(col0 + r) * 1024 + kt + g * 8,
                     &Bs[(i * 256 + w * 64) * 8]);
        }
        __syncthreads();
        #pragma unroll
        for (int ks = 0; ks < 2; ++ks) {
            bf16x8 av[4], bv[2];
            #pragma unroll
            for (int mt = 0; mt < 4; ++mt) {
                const int r = wm + mt * 16 + l16;
                av[mt] = *(const bf16x8*)&As[r * 64 + ((ks * 4 + quad) ^ sw) * 8];
            }
            #pragma unroll
            for (int nt = 0; nt < 2; ++nt) {
                const int r = wn + nt * 16 + l16;
                bv[nt] = *(const bf16x8*)&Bs[r * 64 + ((ks * 4 + quad) ^ sw) * 8];
            }
            #pragma unroll
            for (int mt = 0; mt < 4; ++mt)
                #pragma unroll
                for (int nt = 0; nt < 2; ++nt)
                    acc[mt][nt] = __builtin_amdgcn_mfma_f32_16x16x32_bf16(
                        av[mt], bv[nt], acc[mt][nt], 0, 0, 0);
        }
    }

    float bvv[2];
    #pragma unroll
    for (int nt = 0; nt < 2; ++nt) bvv[nt] = bias[col0 + wn + nt * 16 + l16];
    #pragma unroll
    for (int mt = 0; mt < 4; ++mt)
        #pragma unroll
        for (int reg = 0; reg < 4; ++reg) {
            const size_t row = row0 + wm + mt * 16 + quad * 4 + reg;
            #pragma unroll
            for (int nt = 0; nt < 2; ++nt) {
                const int col = col0 + wn + nt * 16 + l16;
                C[row * 1024 + col] = f2bs(acc[mt][nt][reg] + bvv[nt]);
            }
        }
}

// ---------------------------------------------------------------------------
// Key permutation pi(k) = (k&15)*4 + (k>>4), applied identically to the key
// axis of P and of VsT (sum over k is order-agnostic). Under pi, a thread's
// 4 P-values per output row become phys cols 4*l16+{0..3} -> one
// ds_write_b64 per row + packed cvt instead of 16 b16 writes + 16 RNE chains.
// R10 lesson (locked): K must stay in LDS -- the per-tile __syncthreads()
// drains vmcnt(0), so direct-from-L2 kf loads land their ~200cy latency on
// the critical path every tile (57 -> 91.7us). LDS staging issues the loads
// a full phase earlier, ahead of the same barrier.
// ---------------------------------------------------------------------------

// softmax(step) + PV for one 16-row q-fragment vs a staged 64-key tile.
// Q is PRE-SCALED by 0.125*log2e in gemm_bt, so scores feed exp2 directly.
// DIAG: only the diagonal tile applies the strict-upper (col > row) mask.
// l-accumulation on the matrix pipe: lacc = mfma(pf, ones, lacc).
// Layouts (HW-validated): A-frag A[m=l16][k=quad*8+j]; B-frag
// B[k=quad*8+j][n=l16]; C/D row=quad*4+reg, col=l16.
template<bool DIAG>
__device__ __forceinline__ void qtile_step(
    const bf16x8 (&qf)[2],
    const short (&Ks)[64][72], const short (&VsT)[64][72],
    short (&Psw)[16][72],
    const int k0, const int row_base,
    const int quad, const int l16,
    const bf16x8 ones,
    f32x4 &lacc, f32x4 (&O)[4])
{
    bf16x8 kf[2][4];
    #pragma unroll
    for (int ks = 0; ks < 2; ++ks)
        #pragma unroll
        for (int nt = 0; nt < 4; ++nt)
            kf[ks][nt] = *(const bf16x8*)&Ks[nt * 16 + l16][ks * 32 + quad * 8];

    f32x4 S[4] = {};
    __builtin_amdgcn_s_setprio(1);
    #pragma unroll
    for (int ks = 0; ks < 2; ++ks)
        #pragma unroll
        for (int nt = 0; nt < 4; ++nt)
            S[nt] = __builtin_amdgcn_mfma_f32_16x16x32_bf16(qf[ks], kf[ks][nt], S[nt], 0, 0, 0);
    __builtin_amdgcn_s_setprio(0);

    // clamp 115.4 == old exp(<=80); mask -126 -> 2^-126 ~= old exp(-87).
    #pragma unroll
    for (int nt = 0; nt < 4; ++nt) {
        #pragma unroll
        for (int reg = 0; reg < 4; ++reg) {
            float s = fminf(S[nt][reg], 115.4f);
            if (DIAG) {
                const int col = k0 + nt * 16 + l16;
                const int row = row_base + quad * 4 + reg;
                s = (col > row) ? s : -126.0f;
            }
            S[nt][reg] = exp2f(s);
        }
    }

    // publish P: per output row, pack 4 values (phys cols 4*l16+0..3) -> b64
    #pragma unroll
    for (int reg = 0; reg < 4; ++reg) {
        const __hip_bfloat162 lo = __float22bfloat162_rn(make_float2(S[0][reg], S[1][reg]));
        const __hip_bfloat162 hi = __float22bfloat162_rn(make_float2(S[2][reg], S[3][reg]));
        uint2 u;
        u.x = *reinterpret_cast<const unsigned int*>(&lo);
        u.y = *reinterpret_cast<const unsigned int*>(&hi);
        *(uint2*)&Psw[quad * 4 + reg][l16 * 4] = u;
    }

    __builtin_amdgcn_s_setprio(1);
    #pragma unroll
    for (int ks = 0; ks < 2; ++ks) {
        const bf16x8 pf = *(const bf16x8*)&Psw[l16][ks * 32 + quad * 8];
        lacc = __builtin_amdgcn_mfma_f32_16x16x32_bf16(pf, ones, lacc, 0, 0, 0);
        #pragma unroll
        for (int nt = 0; nt < 4; ++nt) {
            const bf16x8 vf = *(const bf16x8*)&VsT[nt * 16 + l16][ks * 32 + quad * 8];
            O[nt] = __builtin_amdgcn_mfma_f32_16x16x32_bf16(pf, vf, O[nt], 0, 0, 0);
        }
    }
    __builtin_amdgcn_s_setprio(0);
}

// ---------------------------------------------------------------------------
// Pair-SEQUENTIAL MFMA flash attention (R9 exact kernel, measured 57.0us x3),
// strict-upper mask (attend j > i), vmean fused as concurrent blocks.
// Grid (16,17,2): y<16 -> attn (512 blocks, uniform 33 tiles each);
// y==16 -> vmean (32 blocks, hidden under attn).
// K/V double-buffered in LDS, ONE barrier per key tile; XCD remap (FETCH
// 12-16MB, L2-resident working set).
// ---------------------------------------------------------------------------
__global__ __launch_bounds__(256, 3) void attn_mfma(
    const short* __restrict__ Qg, const short* __restrict__ Kg,
    const short* __restrict__ Vg, short* __restrict__ CTX)
{
    __shared__ __align__(16) short Ks [2][64][72];   // [buf][key][d]
    __shared__ __align__(16) short VsT[2][64][72];   // [buf][d][pi(key)]
    __shared__ __align__(16) short Ps[4][16][72];    // per-wave P scratch
    __shared__ float red[4][64];                     // vmean reduction

    const int tid  = threadIdx.x;

    if (blockIdx.y == 16) {   // ---- vmean path (concurrent) ----
        const int h = blockIdx.x, b = blockIdx.z;
        const int dh = tid & 63, ck = tid >> 6;      // 4 chunks of 512 keys
        float s = 0.f;
        const short* vp = Vg + ((size_t)b * Sc + ck * 512) * Dc + h * DHc + dh;
        for (int j = 0; j < 512; ++j) s += bs2f(vp[(size_t)j * Dc]);
        red[ck][dh] = s;
        __syncthreads();
        if (ck == 0) {
            const float tot = (red[0][dh] + red[1][dh] + red[2][dh] + red[3][dh]) * (1.f / Sc);
            CTX[((size_t)b * Sc + Sc - 1) * Dc + h * DHc + dh] = f2bs(tot);
        }
        return;
    }

    // ---- attn path ----
    const int lane = tid & 63, w = tid >> 6;         // w 0..3
    const int quad = lane >> 4, l16 = lane & 15;

    // XCD-locality decode (flat = x+16y+272z -> xcd = x&7; each XCD owns 4
    // complete (b,h) groups, all 16 pairs)
    const int xcd   = blockIdx.x & 7;
    const int local = (blockIdx.x >> 3) + 2 * blockIdx.y + 32 * blockIdx.z;  // 0..63
    const int bh    = xcd * 4 + (local >> 4);
    const int p     = local & 15;
    const int h     = bh & 15;
    const int b     = bh >> 4;
    const size_t rb = (size_t)b * Sc;
    const int cb = h * DHc;

    // staging: 256 threads; thread stages key row skey, d-segs sseg & sseg+32
    const int skey = tid & 63, sseg = (tid >> 6) * 8;
    const int pkey = ((skey & 15) << 2) | (skey >> 4);   // pi(skey)

    bf16x8 ones;
    #pragma unroll
    for (int e = 0; e < 8; ++e) ones[e] = (short)0x3F80;   // bf16 1.0

    const size_t tstride = (size_t)64 * Dc;

    #pragma unroll 1
    for (int ph = 0; ph < 2; ++ph) {
        const int myq = ph ? (NT - 1 - p) : p;   // q-tile index 0..31
        const int t0  = myq;
        const int q0  = myq * 64;

        bf16x8 qf[2];
        {
            const short* qp = Qg + (rb + q0 + w * 16 + l16) * (size_t)Dc + cb + quad * 8;
            qf[0] = *(const bf16x8*)(qp);
            qf[1] = *(const bf16x8*)(qp + 32);
        }
        f32x4 lacc = {};
        f32x4 O[4] = {};

        // strength-reduced staging pointers (advance by 64*Dc per tile)
        const short* kp = Kg + (rb + (size_t)t0 * 64 + skey) * Dc + cb + sseg;
        const short* vp = Vg + (rb + (size_t)t0 * 64 + skey) * Dc + cb + sseg;

        if (ph) __syncthreads();   // phase A waves may still be reading bufs

        {   // stage first tile t0 into buf t0&1
            const int buf = t0 & 1;
            const bf16x8 k0v = *(const bf16x8*)(kp);
            const bf16x8 k1v = *(const bf16x8*)(kp + 32);
            const bf16x8 v0v = *(const bf16x8*)(vp);
            const bf16x8 v1v = *(const bf16x8*)(vp + 32);
            *(bf16x8*)&Ks[buf][skey][sseg]      = k0v;
            *(bf16x8*)&Ks[buf][skey][sseg + 32] = k1v;
            #pragma unroll
            for (int e = 0; e < 8; ++e) {
                VsT[buf][sseg + e][pkey]      = v0v[e];
                VsT[buf][sseg + 32 + e][pkey] = v1v[e];
            }
        }
        __syncthreads();

        for (int t = t0; t < NT; ++t) {
            const int cur = t & 1;
            const bool havenext = (t + 1 < NT);
            bf16x8 pk0, pk1, pv0, pv1;
            if (havenext) {   // register prefetch of tile t+1
                pk0 = *(const bf16x8*)(kp + tstride);
                pk1 = *(const bf16x8*)(kp + tstride + 32);
                pv0 = *(const bf16x8*)(vp + tstride);
                pv1 = *(const bf16x8*)(vp + tstride + 32);
            }

            if (t == t0)
                qtile_step<true >(qf, Ks[cur], VsT[cur], Ps[w],
                                  t * 64, q0 + w * 16, quad, l16, ones, lacc, O);
            else
                qtile_step<false>(qf, Ks[cur], VsT[cur], Ps[w],
                                  t * 64, q0 + w * 16, quad, l16, ones, lacc, O);

            if (havenext) {   // stage tile t+1 into the other buffer, ONE barrier
                const int nb = cur ^ 1;
                *(bf16x8*)&Ks[nb][skey][sseg]      = pk0;
                *(bf16x8*)&Ks[nb][skey][sseg + 32] = pk1;
                #pragma unroll
                for (int e = 0; e < 8; ++e) {
                    VsT[nb][sseg + e][pkey]      = pv0[e];
                    VsT[nb][sseg + 32 + e][pkey] = pv1[e];
                }
                __syncthreads();
            }
            kp += tstride;
            vp += tstride;
        }

        // normalize + store; skip row S-1 (owned by the fused vmean blocks)
        float inv[4];
        #pragma unroll
        for (int reg = 0; reg < 4; ++reg) inv[reg] = 1.0f / lacc[reg];
        #pragma unroll
        for (int nt = 0; nt < 4; ++nt)
            #pragma unroll
            for (int reg = 0; reg < 4; ++reg) {
                const int lr = q0 + w * 16 + quad * 4 + reg;
                if (lr != Sc - 1)
                    CTX[(rb + lr) * Dc + cb + nt * 16 + l16] = f2bs(O[nt][reg] * inv[reg]);
            }
    }
}

// ---------------------------------------------------------------------------
// out = LayerNorm(x + attn_out) * gamma + beta; x f32, AO bf16, out f32
// ---------------------------------------------------------------------------
__global__ __launch_bounds__(256, 4) void resid_ln(
    const float* __restrict__ X, const short* __restrict__ AO,
    const float* __restrict__ gamma, const float* __restrict__ beta,
    float* __restrict__ out)
{
    const int r = blockIdx.x;
    const int t = threadIdx.x;
    const size_t base = (size_t)r * Dc + t * 4;

    const float4 x4 = *(const float4*)(X + base);
    const ushort4 a4 = *(const ushort4*)(AO + base);
    float y[4];
    y[0] = x4.x + bs2f(a4.x);
    y[1] = x4.y + bs2f(a4.y);
    y[2] = x4.z + bs2f(a4.z);
    y[3] = x4.w + bs2f(a4.w);

    float s  = y[0] + y[1] + y[2] + y[3];
    float s2 = y[0]*y[0] + y[1]*y[1] + y[2]*y[2] + y[3]*y[3];
    #pragma unroll
    for (int off = 1; off < 64; off <<= 1) {
        s  += __shfl_xor(s,  off, 64);
        s2 += __shfl_xor(s2, off, 64);
    }
    __shared__ float red[8];
    const int w = t >> 6;
    if ((t & 63) == 0) { red[w] = s; red[4 + w] = s2; }
    __syncthreads();
    s  = red[0] + red[1] + red[2] + red[3];
    s2 = red[4] + red[5] + red[6] + red[7];

    const float mu   = s * (1.0f / Dc);
    const float rstd = rsqrtf(s2 * (1.0f / Dc) - mu * mu + 1e-6f);

    const float4 g4 = *(const float4*)(gamma + t * 4);
    const float4 b4 = *(const float4*)(beta  + t * 4);
    float4 o;
    o.x = (y[0] - mu) * rstd * g4.x + b4.x;
    o.y = (y[1] - mu) * rstd * g4.y + b4.y;
    o.z = (y[2] - mu) * rstd * g4.z + b4.z;
    o.w = (y[3] - mu) * rstd * g4.w + b4.w;
    *(float4*)(out + base) = o;
}

// ---------------------------------------------------------------------------
extern "C" void kernel_launch(void* const* d_in, const int* in_sizes, int n_in,
                              void* d_out, int out_size, void* d_ws, size_t ws_size,
                              hipStream_t stream)
{
    (void)in_sizes; (void)n_in; (void)out_size; (void)ws_size;
    const float* x     = (const float*)d_in[0];
    const float* Wq    = (const float*)d_in[1];
    const float* bq    = (const float*)d_in[2];
    const float* Wk    = (const float*)d_in[3];
    const float* bk    = (const float*)d_in[4];
    const float* Wv    = (const float*)d_in[5];
    const float* bv    = (const float*)d_in[6];
    const float* Wo    = (const float*)d_in[7];
    const float* bo    = (const float*)d_in[8];
    const float* gamma = (const float*)d_in[9];
    const float* beta  = (const float*)d_in[10];
    float* out = (float*)d_out;

    const size_t matN = (size_t)BS * Dc;       // 4,194,304
    const size_t wN   = (size_t)Dc * Dc;       // 1,048,576
    short* xb = (short*)d_ws;                  // 8 MB
    short* WT = xb + matN;                     // 8 MB (4 transposed weights)
    short* Qb = WT + 4 * wN;                   // 8 MB
    short* Kb = Qb + matN;                     // 8 MB
    short* Vb = Kb + matN;                     // 8 MB
    short* Cx = Vb + matN;                     // 8 MB
    short* AO = Qb;                            // Q dead after attention

    prep<<<5120, 256, 0, stream>>>(x, xb, Wq, Wk, Wv, Wo, WT);

    dim3 gq(Dc / 128, BS / 128, 3);            // (8, 32, 3) = 768 blocks, 3/CU
    gemm_bt<<<gq, 256, 0, stream>>>(xb, WT, bq, bk, bv, Qb, 0.18033688f);

    dim3 ga(16, 17, 2);                        // 512 attn blocks + 32 fused vmean
    attn_mfma<<<ga, 256, 0, stream>>>(Qb, Kb, Vb, Cx);

    dim3 go(Dc / 64, BS / 128, 1);             // (16, 32) = 512 blocks, 2/CU
    gemm_bt_n64<<<go, 256, 0, stream>>>(Cx, WT + 3 * wN, bo, AO);

    resid_ln<<<BS, 256, 0, stream>>>(x, AO, gamma, beta, out);
}